// Round 7
// baseline (1120.373 us; speedup 1.0000x reference)
//
#include <hip/hip_runtime.h>
#include <hip/hip_bf16.h>

// MDGCL fused pipeline v6b for MI355X.
// v5 -> v6: CSR build rewritten as two-level bucketed scatter.
//   v5's k_scatter: 4M random 8B stores -> 247 MB HBM writes (7.7x ampl), 210us.
//   v6: bhist (LDS-binned bucket histogram) -> bscan -> binscatter (LDS multisplit
//   to bucket-major intermediate, coalesced runs) -> bucketsort (one block per
//   bucket, 80-160KB L2-resident dest window, also emits ptr[] for free).
// v6 -> v6b: binscatter split per side (template) -> 35KB LDS/block instead of
//   70KB (occupancy 2->4 blocks/CU, avoids any per-WG LDS-limit risk).
// Entry format reaching SpMM identical to validated v5. 12 dispatches.
#define N_Uc 100000
#define N_Ic 50000
#define Dc   64
#define Ec   2000000
#define Bc   2048
#define Kc   10
#define PDROPc   0.2f
#define INV_Tc   5.0f
#define LHYPERc  0.1f
#define JS 4
#define JCH (Bc/JS)

#define NU64 (N_Uc*Dc)
#define NI64 (N_Ic*Dc)
#define B64  (Bc*Dc)

// flag bits: bit17 = keep L0 chA, bit18 = keep L0 chB, bit19 = keep L1 chA,
// bit20 = keep L1 chB. j < 2^17. bits [29:21] = row-local bucket index (buck only).
#define FB_A0 (1<<17)
#define FB_B0 (1<<18)
#define FB_A1 (1<<19)
#define FB_B1 (1<<20)
#define JMASK 0x1FFFF
#define ENTMASK 0x1FFFFF

// bucketing
#define BSH_U 9              // 512 rows per u bucket
#define BSH_I 8              // 256 cols per i bucket
#define NBK   196            // buckets per side (ceil(100000/512) = ceil(50000/256))
#define CHUNK 4096
#define NB_BIN 489           // ceil(Ec/CHUNK)

// block-range constants (4 rows/block in SpMM)
#define NB_SPU (N_Uc/4)          // 25000
#define NB_SPI (N_Ic/4)          // 12500
#define NB_B   (Bc/4)            // 512

static inline int cdiv(int a, int b){ return (a+b-1)/b; }

__device__ __forceinline__ float wsum(float v){
  #pragma unroll
  for (int m=32; m; m>>=1) v += __shfl_xor(v, m, 64);
  return v;
}
__device__ __forceinline__ float actf(float x){ return x >= 0.f ? x : 0.5f*x; }

// ---------------- bucketed CSR build ----------------
__global__ __launch_bounds__(256) void k_zero_b(int* bhist_u, int* bhist_i){
  const int t = threadIdx.x;
  bhist_u[t] = 0; bhist_i[t] = 0;
}

__global__ __launch_bounds__(256) void k_bhist(const int* __restrict__ rows, const int* __restrict__ cols,
                                               int* bhist_u, int* bhist_i){
  __shared__ int hu[256], hi[256];
  const int t = threadIdx.x;
  hu[t] = 0; hi[t] = 0; __syncthreads();
  const int cb = blockIdx.x*CHUNK;
  #pragma unroll
  for (int q=0;q<16;q++){
    const int e = cb + q*256 + t;
    if (e < Ec){
      atomicAdd(&hu[rows[e]>>BSH_U], 1);
      atomicAdd(&hi[cols[e]>>BSH_I], 1);
    }
  }
  __syncthreads();
  if (hu[t]) atomicAdd(&bhist_u[t], hu[t]);
  if (hi[t]) atomicAdd(&bhist_i[t], hi[t]);
}

// 1 block: exclusive scans of the 196-entry bucket histograms -> bases + cursors
__global__ __launch_bounds__(256) void k_bscan(const int* __restrict__ bhist_u, const int* __restrict__ bhist_i,
                                               int* bbase_u, int* bbase_i, int* bcur_u, int* bcur_i){
  __shared__ int sh[256];
  const int t = threadIdx.x;
  sh[t] = bhist_u[t]; __syncthreads();
  for (int s=1;s<256;s<<=1){ const int v=(t>=s)?sh[t-s]:0; __syncthreads(); sh[t]+=v; __syncthreads(); }
  int excl = t? sh[t-1] : 0;
  bbase_u[t] = excl; bcur_u[t] = excl;
  if (t==255) bbase_u[256] = sh[255];
  __syncthreads();
  sh[t] = bhist_i[t]; __syncthreads();
  for (int s=1;s<256;s<<=1){ const int v=(t>=s)?sh[t-s]:0; __syncthreads(); sh[t]+=v; __syncthreads(); }
  excl = t? sh[t-1] : 0;
  bbase_i[t] = excl; bcur_i[t] = excl;
  if (t==255) bbase_i[256] = sh[255];
}

struct BinArgs {
  const int* rows; const int* cols; const float* adj; const float* keep;
  int* bcur_u; int* bcur_i; int2* buck_u; int2* buck_i;
};

// LDS multisplit, one side per launch (SIDE 0 = u/rows, 1 = i/cols).
// 4096 edges/block -> bucket-major runs in buck. 35KB LDS.
template<int SIDE>
__global__ __launch_bounds__(256) void k_binscatter(BinArgs a){
  __shared__ int h[256];           // per-block bucket counts (kept for flush)
  __shared__ int o[256];           // exclusive offsets (stable)
  __shared__ int cu[256];          // placement cursors
  __shared__ int2 st[CHUNK];       // 32 KB staging
  const int t = threadIdx.x;
  const int* key   = SIDE ? a.cols : a.rows;
  const int* other = SIDE ? a.rows : a.cols;
  int* bcur  = SIDE ? a.bcur_i : a.bcur_u;
  int2* buck = SIDE ? a.buck_i : a.buck_u;
  const int bsh = SIDE ? BSH_I : BSH_U;
  const int lmask = SIDE ? 255 : 511;
  h[t] = 0; __syncthreads();
  const int cb = blockIdx.x*CHUNK;
  int kk[16];
  #pragma unroll
  for (int q=0;q<16;q++){
    const int e = cb + q*256 + t;
    kk[q] = -1;
    if (e < Ec){
      kk[q] = key[e];
      atomicAdd(&h[kk[q]>>bsh], 1);
    }
  }
  __syncthreads();
  o[t] = h[t]; __syncthreads();
  for (int s=1;s<256;s<<=1){
    const int v=(t>=s)?o[t-s]:0;
    __syncthreads(); o[t]+=v; __syncthreads();
  }
  const int eo = t? o[t-1]:0;
  __syncthreads();
  o[t]=eo; cu[t]=eo;
  __syncthreads();
  #pragma unroll
  for (int q=0;q<16;q++){
    const int e = cb + q*256 + t;
    if (e >= Ec) continue;
    const int k = kk[q];
    const int j = other[e];
    const int ab = __float_as_int(a.adj[e]);
    int fl;
    if (SIDE == 0){
      fl = ((a.keep[(size_t)0*Ec+e] >= PDROPc)? FB_A0:0) | ((a.keep[(size_t)2*Ec+e] >= PDROPc)? FB_B0:0)
         | ((a.keep[(size_t)4*Ec+e] >= PDROPc)? FB_A1:0) | ((a.keep[(size_t)6*Ec+e] >= PDROPc)? FB_B1:0);
    } else {
      fl = ((a.keep[(size_t)1*Ec+e] >= PDROPc)? FB_A0:0) | ((a.keep[(size_t)3*Ec+e] >= PDROPc)? FB_B0:0)
         | ((a.keep[(size_t)5*Ec+e] >= PDROPc)? FB_A1:0) | ((a.keep[(size_t)7*Ec+e] >= PDROPc)? FB_B1:0);
    }
    const int sl = atomicAdd(&cu[k>>bsh], 1);
    st[sl] = make_int2(j | fl | ((k & lmask) << 21), ab);
  }
  __syncthreads();
  // flush: wave wv handles buckets wv*49 .. wv*49+48 (4 waves x 49 = 196)
  const int wv = t>>6, lane = t&63;
  for (int bb=0; bb<49; ++bb){
    const int b = wv*49 + bb;
    const int cnt = h[b];
    if (cnt){
      int gb;
      if (lane==0) gb = atomicAdd(&bcur[b], cnt);
      gb = __shfl(gb, 0, 64);
      for (int k=lane; k<cnt; k+=64) buck[gb+k] = st[o[b]+k];
    }
  }
}

struct SortArgs {
  const int2* buck_u; const int2* buck_i;
  const int* bbase_u; const int* bbase_i;
  int* ptr_u; int* ptr_i; int2* ent_u; int2* ent_i;
};

// one block per bucket: count rows -> scan -> write ptr -> place entries.
// blocks [0,196) u (512 rows/bucket), [196,392) i (256 cols/bucket).
__global__ __launch_bounds__(512) void k_bucketsort(SortArgs a){
  __shared__ int cnt[512], off[512];
  const int t = threadIdx.x;
  const bool isU = blockIdx.x < NBK;
  const int b = isU ? blockIdx.x : blockIdx.x - NBK;
  const int2* buck = isU ? a.buck_u : a.buck_i;
  const int* bbase = isU ? a.bbase_u : a.bbase_i;
  int* ptr = isU ? a.ptr_u : a.ptr_i;
  int2* ent = isU ? a.ent_u : a.ent_i;
  const int rows_per = isU ? 512 : 256;
  const int r0 = b * rows_per;
  const int n = isU ? N_Uc : N_Ic;
  const int base = bbase[b], tot = bbase[b+1] - base;
  cnt[t] = 0; __syncthreads();
  for (int k=t; k<tot; k+=512){
    const int rl = (buck[base+k].x >> 21) & 511;
    atomicAdd(&cnt[rl], 1);
  }
  __syncthreads();
  off[t] = cnt[t]; __syncthreads();
  for (int s=1;s<512;s<<=1){ const int v=(t>=s)?off[t-s]:0; __syncthreads(); off[t]+=v; __syncthreads(); }
  const int excl = t? off[t-1] : 0;
  if (t < rows_per && r0 + t <= n) ptr[r0 + t] = base + excl;
  __syncthreads();
  cnt[t] = base + excl;          // per-row cursor
  __syncthreads();
  for (int k=t; k<tot; k+=512){
    const int2 w = buck[base+k];
    const int rl = (w.x >> 21) & 511;
    const int pos = atomicAdd(&cnt[rl], 1);
    ent[pos] = make_int2(w.x & ENTMASK, w.y);
  }
}

// ---------------- SpMM device helpers (float4 / 16-lane row-slices) ----------------
// Wave layout: qid = lane>>4 (edge-group slot 0..3), m16 = lane&15 (dims 4*m16..+3).

// layer-0 3-channel body. a0: dropA, a1: adj (S channel), a2: dropB.
__device__ __forceinline__ void dev_spmm3(const int* __restrict__ ptr, const int2* __restrict__ ent,
                                          const float* __restrict__ X, const float* __restrict__ E0,
                                          float* __restrict__ Ec0, float* __restrict__ Ec1,
                                          float* __restrict__ Ec2, float* __restrict__ Etot,
                                          int row, int lane){
  const int beg = ptr[row], end = ptr[row+1];
  const int qid = lane >> 4, m16 = lane & 15;
  float4 a0 = make_float4(0,0,0,0), a1 = a0, a2 = a0;
  for (int base = beg; base < end; base += 64){
    const int rem = end - base;
    int pj = 0; float av = 0.f;
    if (lane < rem){
      const int2 en = ent[base + lane];
      pj = en.x; av = __int_as_float(en.y);
    }
    const int cnt = rem < 64 ? rem : 64;
    for (int g = 0; g < cnt; g += 8){
      const int iA = g + qid,     iB = g + 4 + qid;          // always < 64
      const int pA = __shfl(pj, iA, 64), pB = __shfl(pj, iB, 64);
      float wA = __shfl(av, iA, 64),     wB = __shfl(av, iB, 64);
      wA = (iA < cnt) ? wA : 0.f;
      wB = (iB < cnt) ? wB : 0.f;
      const float4 xA = *(const float4*)(X + (((size_t)(pA & JMASK)) << 6) + (m16 << 2));
      const float4 xB = *(const float4*)(X + (((size_t)(pB & JMASK)) << 6) + (m16 << 2));
      const float kA = wA*1.25f, kB = wB*1.25f;
      const float aA = (pA & FB_A0)? kA:0.f, bA = (pA & FB_B0)? kA:0.f;
      const float aB = (pB & FB_A0)? kB:0.f, bB = (pB & FB_B0)? kB:0.f;
      a1.x = fmaf(wA,xA.x,a1.x); a1.y = fmaf(wA,xA.y,a1.y); a1.z = fmaf(wA,xA.z,a1.z); a1.w = fmaf(wA,xA.w,a1.w);
      a0.x = fmaf(aA,xA.x,a0.x); a0.y = fmaf(aA,xA.y,a0.y); a0.z = fmaf(aA,xA.z,a0.z); a0.w = fmaf(aA,xA.w,a0.w);
      a2.x = fmaf(bA,xA.x,a2.x); a2.y = fmaf(bA,xA.y,a2.y); a2.z = fmaf(bA,xA.z,a2.z); a2.w = fmaf(bA,xA.w,a2.w);
      a1.x = fmaf(wB,xB.x,a1.x); a1.y = fmaf(wB,xB.y,a1.y); a1.z = fmaf(wB,xB.z,a1.z); a1.w = fmaf(wB,xB.w,a1.w);
      a0.x = fmaf(aB,xB.x,a0.x); a0.y = fmaf(aB,xB.y,a0.y); a0.z = fmaf(aB,xB.z,a0.z); a0.w = fmaf(aB,xB.w,a0.w);
      a2.x = fmaf(bB,xB.x,a2.x); a2.y = fmaf(bB,xB.y,a2.y); a2.z = fmaf(bB,xB.z,a2.z); a2.w = fmaf(bB,xB.w,a2.w);
    }
  }
  #pragma unroll
  for (int off = 16; off <= 32; off <<= 1){
    a0.x += __shfl_xor(a0.x, off, 64); a0.y += __shfl_xor(a0.y, off, 64);
    a0.z += __shfl_xor(a0.z, off, 64); a0.w += __shfl_xor(a0.w, off, 64);
    a1.x += __shfl_xor(a1.x, off, 64); a1.y += __shfl_xor(a1.y, off, 64);
    a1.z += __shfl_xor(a1.z, off, 64); a1.w += __shfl_xor(a1.w, off, 64);
    a2.x += __shfl_xor(a2.x, off, 64); a2.y += __shfl_xor(a2.y, off, 64);
    a2.z += __shfl_xor(a2.z, off, 64); a2.w += __shfl_xor(a2.w, off, 64);
  }
  const size_t o = ((size_t)row << 6) + (m16 << 2);
  const float4 e0 = *(const float4*)(E0 + o);
  if (qid == 0){
    float4 r; r.x = e0.x+actf(a0.x); r.y = e0.y+actf(a0.y); r.z = e0.z+actf(a0.z); r.w = e0.w+actf(a0.w);
    *(float4*)(Ec0 + o) = r;
  } else if (qid == 1){
    float4 r; r.x = e0.x+actf(a1.x); r.y = e0.y+actf(a1.y); r.z = e0.z+actf(a1.z); r.w = e0.w+actf(a1.w);
    *(float4*)(Ec1 + o) = r;
  } else if (qid == 2){
    float4 r; r.x = e0.x+actf(a2.x); r.y = e0.y+actf(a2.y); r.z = e0.z+actf(a2.z); r.w = e0.w+actf(a2.w);
    *(float4*)(Ec2 + o) = r;
  } else {
    float4 r; r.x = 2.f*e0.x+actf(a0.x); r.y = 2.f*e0.y+actf(a0.y); r.z = 2.f*e0.z+actf(a0.z); r.w = 2.f*e0.w+actf(a0.w);
    *(float4*)(Etot + o) = r;
  }
}

// layer-1 channel-0 body. Etot += 2*D0 - E0 + act(a0).
__device__ __forceinline__ void dev_spmm1(const int* __restrict__ ptr, const int2* __restrict__ ent,
                                          const float* __restrict__ S, const float* __restrict__ D0,
                                          const float* __restrict__ E0, float* __restrict__ Etot,
                                          int row, int lane){
  const int beg = ptr[row], end = ptr[row+1];
  const int qid = lane >> 4, m16 = lane & 15;
  float4 a0 = make_float4(0,0,0,0);
  for (int base = beg; base < end; base += 64){
    const int rem = end - base;
    int pj = 0; float av = 0.f;
    if (lane < rem){
      const int2 en = ent[base + lane];
      pj = en.x; av = __int_as_float(en.y);
    }
    const int cnt = rem < 64 ? rem : 64;
    for (int g = 0; g < cnt; g += 8){
      const int iA = g + qid,     iB = g + 4 + qid;
      const int pA = __shfl(pj, iA, 64), pB = __shfl(pj, iB, 64);
      float wA = __shfl(av, iA, 64),     wB = __shfl(av, iB, 64);
      wA = (iA < cnt && (pA & FB_A1)) ? wA*1.25f : 0.f;
      wB = (iB < cnt && (pB & FB_A1)) ? wB*1.25f : 0.f;
      const float4 xA = *(const float4*)(S + (((size_t)(pA & JMASK)) << 6) + (m16 << 2));
      const float4 xB = *(const float4*)(S + (((size_t)(pB & JMASK)) << 6) + (m16 << 2));
      a0.x = fmaf(wA,xA.x,a0.x); a0.y = fmaf(wA,xA.y,a0.y); a0.z = fmaf(wA,xA.z,a0.z); a0.w = fmaf(wA,xA.w,a0.w);
      a0.x = fmaf(wB,xB.x,a0.x); a0.y = fmaf(wB,xB.y,a0.y); a0.z = fmaf(wB,xB.z,a0.z); a0.w = fmaf(wB,xB.w,a0.w);
    }
  }
  #pragma unroll
  for (int off = 16; off <= 32; off <<= 1){
    a0.x += __shfl_xor(a0.x, off, 64); a0.y += __shfl_xor(a0.y, off, 64);
    a0.z += __shfl_xor(a0.z, off, 64); a0.w += __shfl_xor(a0.w, off, 64);
  }
  if (qid == 0){
    const size_t o = ((size_t)row << 6) + (m16 << 2);
    const float4 d0 = *(const float4*)(D0 + o);
    const float4 e0 = *(const float4*)(E0 + o);
    float4 et = *(float4*)(Etot + o);
    et.x += 2.f*d0.x - e0.x + actf(a0.x);
    et.y += 2.f*d0.y - e0.y + actf(a0.y);
    et.z += 2.f*d0.z - e0.z + actf(a0.z);
    et.w += 2.f*d0.w - e0.w + actf(a0.w);
    *(float4*)(Etot + o) = et;
  }
}

// sampled 3-channel layer-1 body (2048 rows/side), scalar (tiny traffic).
__device__ __forceinline__ void dev_sspmm(const int* __restrict__ ids, const int* __restrict__ ptr,
                                          const int2* __restrict__ ent,
                                          const float* __restrict__ S0, const float* __restrict__ S1,
                                          const float* __restrict__ S2,
                                          const float* __restrict__ D0, const float* __restrict__ D1,
                                          const float* __restrict__ D2, const float* __restrict__ E0,
                                          float* __restrict__ o0, float* __restrict__ o1,
                                          float* __restrict__ o2, int idx, int lane){
  const int row = ids[idx];
  const int beg = ptr[row], end = ptr[row+1];
  float a0=0.f, a1=0.f, a2=0.f;
  for (int base = beg; base < end; base += 64){
    const int rem = end - base;
    int pj = 0; float av = 0.f;
    if (lane < rem){
      const int2 en = ent[base + lane];
      pj = en.x; av = __int_as_float(en.y);
    }
    const int cnt = rem < 64 ? rem : 64;
    for (int tt=0; tt<cnt; ++tt){
      const int   p = __shfl(pj,tt,64);
      const float w = __shfl(av,tt,64);
      const size_t co = ((size_t)(p&JMASK)<<6)+lane;
      const float x0 = S0[co], x1 = S1[co], x2 = S2[co];
      a1 = fmaf(w, x1, a1);
      a0 = fmaf((p&FB_A1)? w*1.25f:0.f, x0, a0);
      a2 = fmaf((p&FB_B1)? w*1.25f:0.f, x2, a2);
    }
  }
  const size_t o  = ((size_t)idx << 6) + lane;
  const size_t ro = ((size_t)row << 6) + lane;
  const float e0 = E0[ro];
  o0[o] = actf(a0) + D0[ro] - e0;
  o1[o] = actf(a1) + D1[ro] - e0;
  o2[o] = actf(a2) + D2[ro] - e0;
}

__device__ __forceinline__ void dev_gsave0(const int* __restrict__ ids,
                                           const float* __restrict__ D0, const float* __restrict__ D1,
                                           const float* __restrict__ D2, const float* __restrict__ E0,
                                           float* __restrict__ o0, float* __restrict__ o1,
                                           float* __restrict__ o2, int idx, int lane){
  const size_t ro = ((size_t)ids[idx] << 6) + lane;
  const size_t o  = ((size_t)idx << 6) + lane;
  const float e0 = E0[ro];
  o0[o] = D0[ro] - e0; o1[o] = D1[ro] - e0; o2[o] = D2[ro] - e0;
}

// ---------------- merged top-level kernels ----------------
struct SpmmArgs {
  const int* ptr_u; const int2* ent_u;
  const int* ptr_i; const int2* ent_i;
  const float* Eu0; const float* Ei0;
  float* Ecu0; float* Ecu1; float* Ecu2; float* Eut;
  float* Eci0; float* Eci1; float* Eci2; float* Eit;
};

// layer 0: blocks [0,25000) u-dst, [25000,37500) i-dst
__global__ __launch_bounds__(256) void k_spmm3_all(SpmmArgs a){
  const int w = threadIdx.x >> 6, lane = threadIdx.x & 63;
  const int bid = blockIdx.x;
  if (bid < NB_SPU){
    const int row = bid*4 + w;
    dev_spmm3(a.ptr_u, a.ent_u, a.Ei0, a.Eu0, a.Ecu0, a.Ecu1, a.Ecu2, a.Eut, row, lane);
  } else {
    const int row = (bid-NB_SPU)*4 + w;
    dev_spmm3(a.ptr_i, a.ent_i, a.Eu0, a.Ei0, a.Eci0, a.Eci1, a.Eci2, a.Eit, row, lane);
  }
}

struct L1Args {
  const int* ptr_u; const int2* ent_u;
  const int* ptr_i; const int2* ent_i;
  const float* Eu0; const float* Ei0;
  const float* Ecu0; const float* Ecu1; const float* Ecu2;
  const float* Eci0; const float* Eci1; const float* Eci2;
  float* Eut; float* Eit;
  const int* uids; const int* iids;
  float* svu1_0; float* svu1_1; float* svu1_2;
  float* svi1_0; float* svi1_1; float* svi1_2;
  float* svu0_0; float* svu0_1; float* svu0_2;
  float* svi0_0; float* svi0_1; float* svi0_2;
};

__global__ __launch_bounds__(256) void k_layer1_all(L1Args a){
  const int w = threadIdx.x >> 6, lane = threadIdx.x & 63;
  const int bid = blockIdx.x;
  if (bid < NB_SPU){
    dev_spmm1(a.ptr_u, a.ent_u, a.Eci0, a.Ecu0, a.Eu0, a.Eut, bid*4+w, lane);
  } else if (bid < NB_SPU+NB_SPI){
    dev_spmm1(a.ptr_i, a.ent_i, a.Ecu0, a.Eci0, a.Ei0, a.Eit, (bid-NB_SPU)*4+w, lane);
  } else if (bid < NB_SPU+NB_SPI+NB_B){
    dev_sspmm(a.uids, a.ptr_u, a.ent_u, a.Eci0, a.Eci1, a.Eci2,
              a.Ecu0, a.Ecu1, a.Ecu2, a.Eu0, a.svu1_0, a.svu1_1, a.svu1_2,
              (bid-(NB_SPU+NB_SPI))*4+w, lane);
  } else if (bid < NB_SPU+NB_SPI+2*NB_B){
    dev_sspmm(a.iids, a.ptr_i, a.ent_i, a.Ecu0, a.Ecu1, a.Ecu2,
              a.Eci0, a.Eci1, a.Eci2, a.Ei0, a.svi1_0, a.svi1_1, a.svi1_2,
              (bid-(NB_SPU+NB_SPI+NB_B))*4+w, lane);
  } else if (bid < NB_SPU+NB_SPI+3*NB_B){
    dev_gsave0(a.uids, a.Ecu0, a.Ecu1, a.Ecu2, a.Eu0,
               a.svu0_0, a.svu0_1, a.svu0_2, (bid-(NB_SPU+NB_SPI+2*NB_B))*4+w, lane);
  } else {
    dev_gsave0(a.iids, a.Eci0, a.Eci1, a.Eci2, a.Ei0,
               a.svi0_0, a.svi0_1, a.svi0_2, (bid-(NB_SPU+NB_SPI+3*NB_B))*4+w, lane);
  }
}

// ---------------- loss prep: 12 ops x 512 blocks ----------------
struct PrepArgs {
  const float* in[12];
  const float* W[12];
  float* out[12];
};

__global__ __launch_bounds__(256) void k_prep(PrepArgs pa){
  const int op = blockIdx.x >> 9;
  const int sub = blockIdx.x & 511;
  const int w = threadIdx.x >> 6, lane = threadIdx.x & 63;
  const int b = sub*4 + w;
  const float* in = pa.in[op];
  float* out = pa.out[op];
  const size_t o = ((size_t)b << 6) + lane;
  if (op < 8){
    const float v = in[o];
    const float n = fmaxf(sqrtf(wsum(v*v)), 1e-12f);
    out[o] = v/n;
  } else {
    const float* W = pa.W[op];
    const float x  = in[o];
    const float xn = fmaxf(sqrtf(wsum(x*x)), 1e-7f);
    const float sh = sinhf(xn), ch = coshf(xn);
    float vp = sh * x / xn;
    const float nv = fmaxf(sqrtf(ch*ch + wsum(vp*vp)), 1e-12f);
    const float v0 = ch/nv;
    vp /= nv;
    float acc = v0 * W[lane + 1];
    #pragma unroll
    for (int r=0; r<64; ++r){
      const float vr = __shfl(vp, r, 64);
      acc = fmaf(vr, W[(r+1)*65 + lane + 1], acc);
    }
    out[o] = acc;
  }
}

// ---------------- pair scores (8 pairs, 2-row register blocking) + lossr ----------------
struct PairArgs {
  const float* G[8]; const float* H[8];
  float2* pp;                       // [8][Bc][JS]
  const int* uids; const int* pos; const int* neg;
  const float* Eut; const float* Eit;
  float* rbuf;                      // [Bc] loss_r partials
};

__global__ __launch_bounds__(256,2) void k_pair_all(PairArgs pa){
  __shared__ float h_sh[64][68];
  const int bid = blockIdx.x;
  const int t = threadIdx.x;
  if (bid >= 4096){
    const int b = (bid-4096)*4 + (t>>6);
    const int lane = t & 63;
    const float ue = pa.Eut[((size_t)pa.uids[b] << 6) + lane];
    float s = 0.f;
    #pragma unroll
    for (int k=0;k<Kc;k++){
      const float dp = wsum(ue * pa.Eit[((size_t)pa.pos[b*Kc+k] << 6) + lane]);
      const float dn = wsum(ue * pa.Eit[((size_t)pa.neg[b*Kc+k] << 6) + lane]);
      const float tt = 1.f - dp + dn;
      s += tt > 0.f ? tt : 0.f;
    }
    if (lane == 0) pa.rbuf[b] = s;
    return;
  }
  const int pIdx = bid >> 9;
  const int wid = bid & 511;
  const int rg = wid >> 2, jb = wid & 3;
  const float* G = pa.G[pIdx];
  const float* H = pa.H[pIdx];
  const int rp = t >> 5, c = t & 31;
  const int r0 = rg*16 + rp*2;
  float4 g0[16], g1[16];
  {
    const float4* G0 = (const float4*)(G + ((size_t)r0 << 6));
    const float4* G1 = (const float4*)(G + ((size_t)(r0+1) << 6));
    #pragma unroll
    for (int q=0;q<16;q++){ g0[q] = G0[q]; g1[q] = G1[q]; }
  }
  float m0=-1e30f, s0=0.f, m1=-1e30f, s1=0.f;
  for (int jt = jb*JCH; jt < jb*JCH + JCH; jt += 64){
    __syncthreads();
    #pragma unroll
    for (int q0=0;q0<4;q0++){
      const int q = t + q0*256;
      const int row = q >> 4, col = q & 15;
      *(float4*)&h_sh[row][col*4] = ((const float4*)(H + ((size_t)(jt+row) << 6)))[col];
    }
    __syncthreads();
    #pragma unroll
    for (int jj=0; jj<2; ++jj){
      const int j = jj*32 + c;
      float d0 = 0.f, d1 = 0.f;
      #pragma unroll
      for (int q=0;q<16;q++){
        const float4 hv = *(const float4*)&h_sh[j][q*4];
        d0 = fmaf(g0[q].x, hv.x, d0); d0 = fmaf(g0[q].y, hv.y, d0);
        d0 = fmaf(g0[q].z, hv.z, d0); d0 = fmaf(g0[q].w, hv.w, d0);
        d1 = fmaf(g1[q].x, hv.x, d1); d1 = fmaf(g1[q].y, hv.y, d1);
        d1 = fmaf(g1[q].z, hv.z, d1); d1 = fmaf(g1[q].w, hv.w, d1);
      }
      d0 *= INV_Tc; d1 *= INV_Tc;
      { const float M = fmaxf(m0, d0); s0 = fmaf(s0, __expf(m0-M), __expf(d0-M)); m0 = M; }
      { const float M = fmaxf(m1, d1); s1 = fmaf(s1, __expf(m1-M), __expf(d1-M)); m1 = M; }
    }
  }
  #pragma unroll
  for (int off=16; off; off>>=1){
    { const float mo=__shfl_xor(m0,off,64), so=__shfl_xor(s0,off,64);
      const float M=fmaxf(m0,mo); s0 = s0*__expf(m0-M) + so*__expf(mo-M); m0=M; }
    { const float mo=__shfl_xor(m1,off,64), so=__shfl_xor(s1,off,64);
      const float M=fmaxf(m1,mo); s1 = s1*__expf(m1-M) + so*__expf(mo-M); m1=M; }
  }
  if (c == 0){
    float2* pp = pa.pp + (size_t)pIdx*Bc*JS;
    pp[(size_t)r0*JS + jb]     = make_float2(m0, s0);
    pp[(size_t)(r0+1)*JS + jb] = make_float2(m1, s1);
  }
}

// merge: 8 x 512 blocks; per-row result -> mres[pIdx*Bc + b] (no atomics)
struct MergeArgs {
  const float* G[8]; const float* H[8];
  const float2* pp; float* mres;    // [8][Bc]
};

__global__ __launch_bounds__(256) void k_merge_all(MergeArgs ma){
  const int pIdx = blockIdx.x >> 9;
  const int sub = blockIdx.x & 511;
  const int w = threadIdx.x >> 6, lane = threadIdx.x & 63;
  const int b = sub*4 + w;
  const float* G = ma.G[pIdx];
  const float* H = ma.H[pIdx];
  const size_t o = ((size_t)b << 6) + lane;
  const float d = wsum(G[o]*H[o]) * INV_Tc;
  const float2* pp = ma.pp + (size_t)pIdx*Bc*JS + (size_t)b*JS;
  const float2 p0 = pp[0], p1 = pp[1], p2 = pp[2], p3 = pp[3];
  float res;
  if ((pIdx & 1) == 0){
    const float M = fmaxf(fmaxf(p0.x,p1.x), fmaxf(p2.x,p3.x));
    const float S = p0.y*__expf(p0.x-M) + p1.y*__expf(p1.x-M)
                  + p2.y*__expf(p2.x-M) + p3.y*__expf(p3.x-M);
    res = M + logf(S) - d;
  } else {
    const float S = p0.y*__expf(p0.x) + p1.y*__expf(p1.x)
                  + p2.y*__expf(p2.x) + p3.y*__expf(p3.x);
    res = -logf(__expf(d)/(S + 1e-8f) + 1e-8f);
  }
  if (lane == 0) ma.mres[(size_t)pIdx*Bc + b] = res;
}

// final: single block sums rbuf (loss_r) + mres (loss_g even pIdx, loss_h odd)
__global__ __launch_bounds__(256) void k_final(const float* __restrict__ rbuf,
                                               const float* __restrict__ mres,
                                               float* __restrict__ out){
  __shared__ float shm[3][4];
  const int t = threadIdx.x;
  float sr = 0.f, shh = 0.f, sg = 0.f;
  for (int i=t; i<Bc; i+=256) sr += rbuf[i];
  #pragma unroll
  for (int p=0;p<8;p++){
    float acc = 0.f;
    for (int i=t; i<Bc; i+=256) acc += mres[(size_t)p*Bc + i];
    if (p & 1) shh += acc; else sg += acc;
  }
  sr = wsum(sr); shh = wsum(shh); sg = wsum(sg);
  const int w = t >> 6;
  if ((t & 63) == 0){ shm[0][w] = sr; shm[1][w] = shh; shm[2][w] = sg; }
  __syncthreads();
  if (t == 0){
    float R=0.f, Hh=0.f, Gg=0.f;
    #pragma unroll
    for (int q=0;q<4;q++){ R += shm[0][q]; Hh += shm[1][q]; Gg += shm[2][q]; }
    const float lr = R / (float)Bc;
    out[0] = lr + LHYPERc*Hh + Gg;
    out[1] = lr; out[2] = Hh; out[3] = Gg;
  }
}

// ---------------- host launch ----------------
extern "C" void kernel_launch(void* const* d_in, const int* in_sizes, int n_in,
                              void* d_out, int out_size, void* d_ws, size_t ws_size,
                              hipStream_t stream){
  const float* E_u0 = (const float*)d_in[0];
  const float* E_i0 = (const float*)d_in[1];
  // d_in[2], d_in[3] (S_u_0, S_i_0): col 0 == 0 forever, payload == E_*_0 -> unused.
  const float* Ws   = (const float*)d_in[4];
  const float* adj  = (const float*)d_in[5];
  const float* keep = (const float*)d_in[6];
  const int* rows = (const int*)d_in[7];
  const int* cols = (const int*)d_in[8];
  const int* uids = (const int*)d_in[9];
  const int* iids = (const int*)d_in[10];
  const int* pos  = (const int*)d_in[11];
  const int* neg  = (const int*)d_in[12];
  float* out = (float*)d_out;

  char* wsb = (char*)d_ws;
  size_t off = 0;
  auto alloc = [&](size_t bytes)->void*{
    void* p = (void*)(wsb + off);
    off += (bytes + 255) & ~(size_t)255;
    return p;
  };

  int* bhist_u = (int*)alloc(256*4);
  int* bhist_i = (int*)alloc(256*4);
  int* bbase_u = (int*)alloc(257*4);
  int* bbase_i = (int*)alloc(257*4);
  int* bcur_u  = (int*)alloc(256*4);
  int* bcur_i  = (int*)alloc(256*4);
  int* ptr_u = (int*)alloc((size_t)(N_Uc+1)*4);
  int* ptr_i = (int*)alloc((size_t)(N_Ic+1)*4);
  int2* buck_u = (int2*)alloc((size_t)Ec*8);
  int2* buck_i = (int2*)alloc((size_t)Ec*8);
  int2* ent_u = (int2*)alloc((size_t)Ec*8);
  int2* ent_i = (int2*)alloc((size_t)Ec*8);

  float* Ecu0 = (float*)alloc((size_t)NU64*4);
  float* Ecu1 = (float*)alloc((size_t)NU64*4);
  float* Ecu2 = (float*)alloc((size_t)NU64*4);
  float* Eu_t = (float*)alloc((size_t)NU64*4);
  float* Eci0 = (float*)alloc((size_t)NI64*4);
  float* Eci1 = (float*)alloc((size_t)NI64*4);
  float* Eci2 = (float*)alloc((size_t)NI64*4);
  float* Ei_t = (float*)alloc((size_t)NI64*4);

  float* sv_u[2][3], *sv_i[2][3];
  for (int l=0;l<2;l++) for (int ch=0;ch<3;ch++){
    sv_u[l][ch] = (float*)alloc((size_t)B64*4);
    sv_i[l][ch] = (float*)alloc((size_t)B64*4);
  }
  float* nrm_g[4], *nrm_u[4], *hmat[4];
  for (int p=0;p<4;p++){
    nrm_g[p] = (float*)alloc((size_t)B64*4);
    nrm_u[p] = (float*)alloc((size_t)B64*4);
    hmat[p]  = (float*)alloc((size_t)B64*4);
  }
  float2* pp = (float2*)alloc((size_t)8*Bc*JS*8);
  float* rbuf = (float*)alloc((size_t)Bc*4);
  float* mres = (float*)alloc((size_t)8*Bc*4);
  // total ws use ~= 235 MB

  // ---- bucketed CSR/CSC build (6 launches) ----
  k_zero_b<<<1,256,0,stream>>>(bhist_u, bhist_i);
  k_bhist<<<NB_BIN,256,0,stream>>>(rows, cols, bhist_u, bhist_i);
  k_bscan<<<1,256,0,stream>>>(bhist_u, bhist_i, bbase_u, bbase_i, bcur_u, bcur_i);
  BinArgs ba{rows, cols, adj, keep, bcur_u, bcur_i, buck_u, buck_i};
  k_binscatter<0><<<NB_BIN,256,0,stream>>>(ba);
  k_binscatter<1><<<NB_BIN,256,0,stream>>>(ba);
  SortArgs soa{buck_u, buck_i, bbase_u, bbase_i, ptr_u, ptr_i, ent_u, ent_i};
  k_bucketsort<<<2*NBK,512,0,stream>>>(soa);

  // ---- layer 0 (1 launch) ----
  SpmmArgs sa{ptr_u, ent_u, ptr_i, ent_i, E_u0, E_i0,
              Ecu0, Ecu1, Ecu2, Eu_t, Eci0, Eci1, Eci2, Ei_t};
  k_spmm3_all<<<NB_SPU+NB_SPI,256,0,stream>>>(sa);

  // ---- layer 1 + sampled + layer-0 saves (1 launch) ----
  L1Args la{ptr_u, ent_u, ptr_i, ent_i, E_u0, E_i0,
            Ecu0, Ecu1, Ecu2, Eci0, Eci1, Eci2, Eu_t, Ei_t, uids, iids,
            sv_u[1][0], sv_u[1][1], sv_u[1][2], sv_i[1][0], sv_i[1][1], sv_i[1][2],
            sv_u[0][0], sv_u[0][1], sv_u[0][2], sv_i[0][0], sv_i[0][1], sv_i[0][2]};
  k_layer1_all<<<NB_SPU+NB_SPI+4*NB_B,256,0,stream>>>(la);

  // ---- loss prep (1 launch): p = l*2+side ----
  PrepArgs pra{};
  for (int l=0;l<2;l++) for (int side=0; side<2; side++){
    const int p = l*2+side;
    float** svs = side ? sv_i[l] : sv_u[l];
    pra.in[p]   = svs[0]; pra.out[p]   = nrm_g[p];
    pra.in[4+p] = svs[2]; pra.out[4+p] = nrm_u[p];
    pra.in[8+p] = svs[1]; pra.out[8+p] = hmat[p];
    pra.W[8+p]  = Ws + (size_t)l*65*65;
  }
  k_prep<<<12*NB_B,256,0,stream>>>(pra);

  // ---- pair scores + lossr (1 launch) ----
  PairArgs paa{};
  for (int p=0;p<4;p++){
    paa.G[2*p]   = nrm_g[p]; paa.H[2*p]   = nrm_u[p];   // loss_g
    paa.G[2*p+1] = nrm_g[p]; paa.H[2*p+1] = hmat[p];    // loss_h
  }
  paa.pp = pp; paa.uids = uids; paa.pos = pos; paa.neg = neg;
  paa.Eut = Eu_t; paa.Eit = Ei_t; paa.rbuf = rbuf;
  k_pair_all<<<4096+NB_B,256,0,stream>>>(paa);

  // ---- merge (1 launch) + final ----
  MergeArgs mga{};
  for (int p=0;p<8;p++){ mga.G[p] = paa.G[p]; mga.H[p] = paa.H[p]; }
  mga.pp = pp; mga.mres = mres;
  k_merge_all<<<8*NB_B,256,0,stream>>>(mga);

  k_final<<<1,256,0,stream>>>(rbuf, mres, out);
}

// Round 9
// 709.704 us; speedup vs baseline: 1.5786x; 1.5786x over previous
//
#include <hip/hip_runtime.h>
#include <hip/hip_bf16.h>

// MDGCL fused pipeline v7 for MI355X.
// v6b -> v7: binscatter's global-atomic cursor convoy (489 lockstep waves
// serializing on the same 196 bcur addresses -> 247us/side at 1.7% VALU)
// replaced by DETERMINISTIC flush offsets: k_count writes the per-(block,
// bucket) count matrix, k_oscan/k_bbase scan it into exact destinations,
// flush is plain coalesced copies with zero global atomics.
// Entry format reaching SpMM identical to validated v5/v6b. 13 dispatches.
#define N_Uc 100000
#define N_Ic 50000
#define Dc   64
#define Ec   2000000
#define Bc   2048
#define Kc   10
#define PDROPc   0.2f
#define INV_Tc   5.0f
#define LHYPERc  0.1f
#define JS 4
#define JCH (Bc/JS)

#define NU64 (N_Uc*Dc)
#define NI64 (N_Ic*Dc)
#define B64  (Bc*Dc)

// flag bits: bit17 = keep L0 chA, bit18 = keep L0 chB, bit19 = keep L1 chA,
// bit20 = keep L1 chB. j < 2^17. bits [29:21] = row-local bucket index (buck only).
#define FB_A0 (1<<17)
#define FB_B0 (1<<18)
#define FB_A1 (1<<19)
#define FB_B1 (1<<20)
#define JMASK 0x1FFFF
#define ENTMASK 0x1FFFFF

// bucketing
#define BSH_U 9              // 512 rows per u bucket
#define BSH_I 8              // 256 cols per i bucket
#define NBK   196            // buckets per side (ceil(100000/512) = ceil(50000/256))
#define CHUNK 4096
#define NB_BIN 489           // ceil(Ec/CHUNK)

// block-range constants (4 rows/block in SpMM)
#define NB_SPU (N_Uc/4)          // 25000
#define NB_SPI (N_Ic/4)          // 12500
#define NB_B   (Bc/4)            // 512

static inline int cdiv(int a, int b){ return (a+b-1)/b; }

__device__ __forceinline__ float wsum(float v){
  #pragma unroll
  for (int m=32; m; m>>=1) v += __shfl_xor(v, m, 64);
  return v;
}
__device__ __forceinline__ float actf(float x){ return x >= 0.f ? x : 0.5f*x; }

// ---------------- bucketed CSR build (deterministic offsets) ----------------
// cmat layout: [block][bucket] (coalesced write). omat layout: [bucket][block]
// (coalesced write in oscan, uniform scalar read in flush).
__global__ __launch_bounds__(256) void k_count(const int* __restrict__ rows, const int* __restrict__ cols,
                                               int* __restrict__ cmat_u, int* __restrict__ cmat_i){
  __shared__ int hu[256], hi[256];
  const int t = threadIdx.x;
  hu[t] = 0; hi[t] = 0; __syncthreads();
  const int cb = blockIdx.x*CHUNK;
  #pragma unroll
  for (int q=0;q<16;q++){
    const int e = cb + q*256 + t;
    if (e < Ec){
      atomicAdd(&hu[rows[e]>>BSH_U], 1);
      atomicAdd(&hi[cols[e]>>BSH_I], 1);
    }
  }
  __syncthreads();
  if (t < NBK){
    cmat_u[blockIdx.x*NBK + t] = hu[t];
    cmat_i[blockIdx.x*NBK + t] = hi[t];
  }
}

// one block per (side,bucket): scan the 489 per-block counts.
// blocks [0,196) u, [196,392) i.
__global__ __launch_bounds__(512) void k_oscan(const int* __restrict__ cmat_u, const int* __restrict__ cmat_i,
                                               int* __restrict__ omat_u, int* __restrict__ omat_i,
                                               int* __restrict__ btot_u, int* __restrict__ btot_i){
  __shared__ int sh[512];
  const int t = threadIdx.x;
  const bool isU = blockIdx.x < NBK;
  const int b = isU ? blockIdx.x : blockIdx.x - NBK;
  const int* cmat = isU ? cmat_u : cmat_i;
  int* omat = isU ? omat_u : omat_i;
  int* btot = isU ? btot_u : btot_i;
  sh[t] = (t < NB_BIN) ? cmat[t*NBK + b] : 0;
  __syncthreads();
  for (int s=1;s<512;s<<=1){ const int v=(t>=s)?sh[t-s]:0; __syncthreads(); sh[t]+=v; __syncthreads(); }
  const int excl = t ? sh[t-1] : 0;
  if (t < NB_BIN) omat[b*NB_BIN + t] = excl;
  if (t == 511) btot[b] = sh[511];
}

// 1 block: scan 196 bucket totals per side -> bbase[0..196]
__global__ __launch_bounds__(256) void k_bbase(const int* __restrict__ btot_u, const int* __restrict__ btot_i,
                                               int* __restrict__ bbase_u, int* __restrict__ bbase_i){
  __shared__ int sh[256];
  const int t = threadIdx.x;
  sh[t] = (t<NBK) ? btot_u[t] : 0; __syncthreads();
  for (int s=1;s<256;s<<=1){ const int v=(t>=s)?sh[t-s]:0; __syncthreads(); sh[t]+=v; __syncthreads(); }
  if (t < NBK) bbase_u[t] = t ? sh[t-1] : 0;
  if (t == NBK-1) bbase_u[NBK] = sh[t];
  __syncthreads();
  sh[t] = (t<NBK) ? btot_i[t] : 0; __syncthreads();
  for (int s=1;s<256;s<<=1){ const int v=(t>=s)?sh[t-s]:0; __syncthreads(); sh[t]+=v; __syncthreads(); }
  if (t < NBK) bbase_i[t] = t ? sh[t-1] : 0;
  if (t == NBK-1) bbase_i[NBK] = sh[t];
}

struct BinArgs {
  const int* rows; const int* cols; const float* adj; const float* keep;
  const int* omat_u; const int* omat_i;
  const int* bbase_u; const int* bbase_i;
  int2* buck_u; int2* buck_i;
};

// LDS multisplit, one side per launch (SIDE 0 = u/rows, 1 = i/cols).
// 4096 edges/block -> bucket-major runs in buck, at DETERMINISTIC offsets.
template<int SIDE>
__global__ __launch_bounds__(256) void k_binscatter(BinArgs a){
  __shared__ int h[256];           // per-block bucket counts
  __shared__ int o[256];           // exclusive staging offsets
  __shared__ int cu2[256];         // placement cursors
  __shared__ int2 st[CHUNK];       // 32 KB staging
  const int t = threadIdx.x;
  const int* key   = SIDE ? a.cols : a.rows;
  const int* other = SIDE ? a.rows : a.cols;
  const int* omat  = SIDE ? a.omat_i : a.omat_u;
  const int* bbase = SIDE ? a.bbase_i : a.bbase_u;
  int2* buck = SIDE ? a.buck_i : a.buck_u;
  const int bsh = SIDE ? BSH_I : BSH_U;
  const int lmask = SIDE ? 255 : 511;
  h[t] = 0; __syncthreads();
  const int cb = blockIdx.x*CHUNK;
  int kk[16];
  #pragma unroll
  for (int q=0;q<16;q++){
    const int e = cb + q*256 + t;
    kk[q] = -1;
    if (e < Ec){
      kk[q] = key[e];
      atomicAdd(&h[kk[q]>>bsh], 1);
    }
  }
  __syncthreads();
  o[t] = h[t]; __syncthreads();
  for (int s=1;s<256;s<<=1){
    const int v=(t>=s)?o[t-s]:0;
    __syncthreads(); o[t]+=v; __syncthreads();
  }
  const int eo = t? o[t-1]:0;
  __syncthreads();
  o[t]=eo; cu2[t]=eo;
  __syncthreads();
  #pragma unroll
  for (int q=0;q<16;q++){
    const int e = cb + q*256 + t;
    if (e >= Ec) continue;
    const int k = kk[q];
    const int j = other[e];
    const int ab = __float_as_int(a.adj[e]);
    int fl;
    if (SIDE == 0){
      fl = ((a.keep[(size_t)0*Ec+e] >= PDROPc)? FB_A0:0) | ((a.keep[(size_t)2*Ec+e] >= PDROPc)? FB_B0:0)
         | ((a.keep[(size_t)4*Ec+e] >= PDROPc)? FB_A1:0) | ((a.keep[(size_t)6*Ec+e] >= PDROPc)? FB_B1:0);
    } else {
      fl = ((a.keep[(size_t)1*Ec+e] >= PDROPc)? FB_A0:0) | ((a.keep[(size_t)3*Ec+e] >= PDROPc)? FB_B0:0)
         | ((a.keep[(size_t)5*Ec+e] >= PDROPc)? FB_A1:0) | ((a.keep[(size_t)7*Ec+e] >= PDROPc)? FB_B1:0);
    }
    const int sl = atomicAdd(&cu2[k>>bsh], 1);
    st[sl] = make_int2(j | fl | ((k & lmask) << 21), ab);
  }
  __syncthreads();
  // flush: wave wv handles buckets wv*49 .. wv*49+48; offsets are deterministic
  const int wv = t>>6, lane = t&63;
  for (int bb=0; bb<49; ++bb){
    const int b = wv*49 + bb;
    const int cnt = h[b];
    if (cnt){
      const int gb = bbase[b] + omat[b*NB_BIN + blockIdx.x];   // uniform scalar loads
      for (int k=lane; k<cnt; k+=64) buck[gb+k] = st[o[b]+k];
    }
  }
}

struct SortArgs {
  const int2* buck_u; const int2* buck_i;
  const int* bbase_u; const int* bbase_i;
  int* ptr_u; int* ptr_i; int2* ent_u; int2* ent_i;
};

// one block per bucket: count rows -> scan -> write ptr -> place entries.
// blocks [0,196) u (512 rows/bucket), [196,392) i (256 cols/bucket).
__global__ __launch_bounds__(512) void k_bucketsort(SortArgs a){
  __shared__ int cnt[512], off[512];
  const int t = threadIdx.x;
  const bool isU = blockIdx.x < NBK;
  const int b = isU ? blockIdx.x : blockIdx.x - NBK;
  const int2* buck = isU ? a.buck_u : a.buck_i;
  const int* bbase = isU ? a.bbase_u : a.bbase_i;
  int* ptr = isU ? a.ptr_u : a.ptr_i;
  int2* ent = isU ? a.ent_u : a.ent_i;
  const int rows_per = isU ? 512 : 256;
  const int r0 = b * rows_per;
  const int n = isU ? N_Uc : N_Ic;
  const int base = bbase[b], tot = bbase[b+1] - base;
  cnt[t] = 0; __syncthreads();
  for (int k=t; k<tot; k+=512){
    const int rl = (buck[base+k].x >> 21) & 511;
    atomicAdd(&cnt[rl], 1);
  }
  __syncthreads();
  off[t] = cnt[t]; __syncthreads();
  for (int s=1;s<512;s<<=1){ const int v=(t>=s)?off[t-s]:0; __syncthreads(); off[t]+=v; __syncthreads(); }
  const int excl = t? off[t-1] : 0;
  if (t < rows_per && r0 + t <= n) ptr[r0 + t] = base + excl;
  __syncthreads();
  cnt[t] = base + excl;          // per-row cursor
  __syncthreads();
  for (int k=t; k<tot; k+=512){
    const int2 w = buck[base+k];
    const int rl = (w.x >> 21) & 511;
    const int pos = atomicAdd(&cnt[rl], 1);
    ent[pos] = make_int2(w.x & ENTMASK, w.y);
  }
}

// ---------------- SpMM device helpers (float4 / 16-lane row-slices) ----------------
// Wave layout: qid = lane>>4 (edge-group slot 0..3), m16 = lane&15 (dims 4*m16..+3).

// layer-0 3-channel body. a0: dropA, a1: adj (S channel), a2: dropB.
__device__ __forceinline__ void dev_spmm3(const int* __restrict__ ptr, const int2* __restrict__ ent,
                                          const float* __restrict__ X, const float* __restrict__ E0,
                                          float* __restrict__ Ec0, float* __restrict__ Ec1,
                                          float* __restrict__ Ec2, float* __restrict__ Etot,
                                          int row, int lane){
  const int beg = ptr[row], end = ptr[row+1];
  const int qid = lane >> 4, m16 = lane & 15;
  float4 a0 = make_float4(0,0,0,0), a1 = a0, a2 = a0;
  for (int base = beg; base < end; base += 64){
    const int rem = end - base;
    int pj = 0; float av = 0.f;
    if (lane < rem){
      const int2 en = ent[base + lane];
      pj = en.x; av = __int_as_float(en.y);
    }
    const int cnt = rem < 64 ? rem : 64;
    for (int g = 0; g < cnt; g += 8){
      const int iA = g + qid,     iB = g + 4 + qid;          // always < 64
      const int pA = __shfl(pj, iA, 64), pB = __shfl(pj, iB, 64);
      float wA = __shfl(av, iA, 64),     wB = __shfl(av, iB, 64);
      wA = (iA < cnt) ? wA : 0.f;
      wB = (iB < cnt) ? wB : 0.f;
      const float4 xA = *(const float4*)(X + (((size_t)(pA & JMASK)) << 6) + (m16 << 2));
      const float4 xB = *(const float4*)(X + (((size_t)(pB & JMASK)) << 6) + (m16 << 2));
      const float kA = wA*1.25f, kB = wB*1.25f;
      const float aA = (pA & FB_A0)? kA:0.f, bA = (pA & FB_B0)? kA:0.f;
      const float aB = (pB & FB_A0)? kB:0.f, bB = (pB & FB_B0)? kB:0.f;
      a1.x = fmaf(wA,xA.x,a1.x); a1.y = fmaf(wA,xA.y,a1.y); a1.z = fmaf(wA,xA.z,a1.z); a1.w = fmaf(wA,xA.w,a1.w);
      a0.x = fmaf(aA,xA.x,a0.x); a0.y = fmaf(aA,xA.y,a0.y); a0.z = fmaf(aA,xA.z,a0.z); a0.w = fmaf(aA,xA.w,a0.w);
      a2.x = fmaf(bA,xA.x,a2.x); a2.y = fmaf(bA,xA.y,a2.y); a2.z = fmaf(bA,xA.z,a2.z); a2.w = fmaf(bA,xA.w,a2.w);
      a1.x = fmaf(wB,xB.x,a1.x); a1.y = fmaf(wB,xB.y,a1.y); a1.z = fmaf(wB,xB.z,a1.z); a1.w = fmaf(wB,xB.w,a1.w);
      a0.x = fmaf(aB,xB.x,a0.x); a0.y = fmaf(aB,xB.y,a0.y); a0.z = fmaf(aB,xB.z,a0.z); a0.w = fmaf(aB,xB.w,a0.w);
      a2.x = fmaf(bB,xB.x,a2.x); a2.y = fmaf(bB,xB.y,a2.y); a2.z = fmaf(bB,xB.z,a2.z); a2.w = fmaf(bB,xB.w,a2.w);
    }
  }
  #pragma unroll
  for (int off = 16; off <= 32; off <<= 1){
    a0.x += __shfl_xor(a0.x, off, 64); a0.y += __shfl_xor(a0.y, off, 64);
    a0.z += __shfl_xor(a0.z, off, 64); a0.w += __shfl_xor(a0.w, off, 64);
    a1.x += __shfl_xor(a1.x, off, 64); a1.y += __shfl_xor(a1.y, off, 64);
    a1.z += __shfl_xor(a1.z, off, 64); a1.w += __shfl_xor(a1.w, off, 64);
    a2.x += __shfl_xor(a2.x, off, 64); a2.y += __shfl_xor(a2.y, off, 64);
    a2.z += __shfl_xor(a2.z, off, 64); a2.w += __shfl_xor(a2.w, off, 64);
  }
  const size_t o = ((size_t)row << 6) + (m16 << 2);
  const float4 e0 = *(const float4*)(E0 + o);
  if (qid == 0){
    float4 r; r.x = e0.x+actf(a0.x); r.y = e0.y+actf(a0.y); r.z = e0.z+actf(a0.z); r.w = e0.w+actf(a0.w);
    *(float4*)(Ec0 + o) = r;
  } else if (qid == 1){
    float4 r; r.x = e0.x+actf(a1.x); r.y = e0.y+actf(a1.y); r.z = e0.z+actf(a1.z); r.w = e0.w+actf(a1.w);
    *(float4*)(Ec1 + o) = r;
  } else if (qid == 2){
    float4 r; r.x = e0.x+actf(a2.x); r.y = e0.y+actf(a2.y); r.z = e0.z+actf(a2.z); r.w = e0.w+actf(a2.w);
    *(float4*)(Ec2 + o) = r;
  } else {
    float4 r; r.x = 2.f*e0.x+actf(a0.x); r.y = 2.f*e0.y+actf(a0.y); r.z = 2.f*e0.z+actf(a0.z); r.w = 2.f*e0.w+actf(a0.w);
    *(float4*)(Etot + o) = r;
  }
}

// layer-1 channel-0 body. Etot += 2*D0 - E0 + act(a0).
__device__ __forceinline__ void dev_spmm1(const int* __restrict__ ptr, const int2* __restrict__ ent,
                                          const float* __restrict__ S, const float* __restrict__ D0,
                                          const float* __restrict__ E0, float* __restrict__ Etot,
                                          int row, int lane){
  const int beg = ptr[row], end = ptr[row+1];
  const int qid = lane >> 4, m16 = lane & 15;
  float4 a0 = make_float4(0,0,0,0);
  for (int base = beg; base < end; base += 64){
    const int rem = end - base;
    int pj = 0; float av = 0.f;
    if (lane < rem){
      const int2 en = ent[base + lane];
      pj = en.x; av = __int_as_float(en.y);
    }
    const int cnt = rem < 64 ? rem : 64;
    for (int g = 0; g < cnt; g += 8){
      const int iA = g + qid,     iB = g + 4 + qid;
      const int pA = __shfl(pj, iA, 64), pB = __shfl(pj, iB, 64);
      float wA = __shfl(av, iA, 64),     wB = __shfl(av, iB, 64);
      wA = (iA < cnt && (pA & FB_A1)) ? wA*1.25f : 0.f;
      wB = (iB < cnt && (pB & FB_A1)) ? wB*1.25f : 0.f;
      const float4 xA = *(const float4*)(S + (((size_t)(pA & JMASK)) << 6) + (m16 << 2));
      const float4 xB = *(const float4*)(S + (((size_t)(pB & JMASK)) << 6) + (m16 << 2));
      a0.x = fmaf(wA,xA.x,a0.x); a0.y = fmaf(wA,xA.y,a0.y); a0.z = fmaf(wA,xA.z,a0.z); a0.w = fmaf(wA,xA.w,a0.w);
      a0.x = fmaf(wB,xB.x,a0.x); a0.y = fmaf(wB,xB.y,a0.y); a0.z = fmaf(wB,xB.z,a0.z); a0.w = fmaf(wB,xB.w,a0.w);
    }
  }
  #pragma unroll
  for (int off = 16; off <= 32; off <<= 1){
    a0.x += __shfl_xor(a0.x, off, 64); a0.y += __shfl_xor(a0.y, off, 64);
    a0.z += __shfl_xor(a0.z, off, 64); a0.w += __shfl_xor(a0.w, off, 64);
  }
  if (qid == 0){
    const size_t o = ((size_t)row << 6) + (m16 << 2);
    const float4 d0 = *(const float4*)(D0 + o);
    const float4 e0 = *(const float4*)(E0 + o);
    float4 et = *(float4*)(Etot + o);
    et.x += 2.f*d0.x - e0.x + actf(a0.x);
    et.y += 2.f*d0.y - e0.y + actf(a0.y);
    et.z += 2.f*d0.z - e0.z + actf(a0.z);
    et.w += 2.f*d0.w - e0.w + actf(a0.w);
    *(float4*)(Etot + o) = et;
  }
}

// sampled 3-channel layer-1 body (2048 rows/side), scalar (tiny traffic).
__device__ __forceinline__ void dev_sspmm(const int* __restrict__ ids, const int* __restrict__ ptr,
                                          const int2* __restrict__ ent,
                                          const float* __restrict__ S0, const float* __restrict__ S1,
                                          const float* __restrict__ S2,
                                          const float* __restrict__ D0, const float* __restrict__ D1,
                                          const float* __restrict__ D2, const float* __restrict__ E0,
                                          float* __restrict__ o0, float* __restrict__ o1,
                                          float* __restrict__ o2, int idx, int lane){
  const int row = ids[idx];
  const int beg = ptr[row], end = ptr[row+1];
  float a0=0.f, a1=0.f, a2=0.f;
  for (int base = beg; base < end; base += 64){
    const int rem = end - base;
    int pj = 0; float av = 0.f;
    if (lane < rem){
      const int2 en = ent[base + lane];
      pj = en.x; av = __int_as_float(en.y);
    }
    const int cnt = rem < 64 ? rem : 64;
    for (int tt=0; tt<cnt; ++tt){
      const int   p = __shfl(pj,tt,64);
      const float w = __shfl(av,tt,64);
      const size_t co = ((size_t)(p&JMASK)<<6)+lane;
      const float x0 = S0[co], x1 = S1[co], x2 = S2[co];
      a1 = fmaf(w, x1, a1);
      a0 = fmaf((p&FB_A1)? w*1.25f:0.f, x0, a0);
      a2 = fmaf((p&FB_B1)? w*1.25f:0.f, x2, a2);
    }
  }
  const size_t o  = ((size_t)idx << 6) + lane;
  const size_t ro = ((size_t)row << 6) + lane;
  const float e0 = E0[ro];
  o0[o] = actf(a0) + D0[ro] - e0;
  o1[o] = actf(a1) + D1[ro] - e0;
  o2[o] = actf(a2) + D2[ro] - e0;
}

__device__ __forceinline__ void dev_gsave0(const int* __restrict__ ids,
                                           const float* __restrict__ D0, const float* __restrict__ D1,
                                           const float* __restrict__ D2, const float* __restrict__ E0,
                                           float* __restrict__ o0, float* __restrict__ o1,
                                           float* __restrict__ o2, int idx, int lane){
  const size_t ro = ((size_t)ids[idx] << 6) + lane;
  const size_t o  = ((size_t)idx << 6) + lane;
  const float e0 = E0[ro];
  o0[o] = D0[ro] - e0; o1[o] = D1[ro] - e0; o2[o] = D2[ro] - e0;
}

// ---------------- merged top-level kernels ----------------
struct SpmmArgs {
  const int* ptr_u; const int2* ent_u;
  const int* ptr_i; const int2* ent_i;
  const float* Eu0; const float* Ei0;
  float* Ecu0; float* Ecu1; float* Ecu2; float* Eut;
  float* Eci0; float* Eci1; float* Eci2; float* Eit;
};

// layer 0: blocks [0,25000) u-dst, [25000,37500) i-dst
__global__ __launch_bounds__(256) void k_spmm3_all(SpmmArgs a){
  const int w = threadIdx.x >> 6, lane = threadIdx.x & 63;
  const int bid = blockIdx.x;
  if (bid < NB_SPU){
    const int row = bid*4 + w;
    dev_spmm3(a.ptr_u, a.ent_u, a.Ei0, a.Eu0, a.Ecu0, a.Ecu1, a.Ecu2, a.Eut, row, lane);
  } else {
    const int row = (bid-NB_SPU)*4 + w;
    dev_spmm3(a.ptr_i, a.ent_i, a.Eu0, a.Ei0, a.Eci0, a.Eci1, a.Eci2, a.Eit, row, lane);
  }
}

struct L1Args {
  const int* ptr_u; const int2* ent_u;
  const int* ptr_i; const int2* ent_i;
  const float* Eu0; const float* Ei0;
  const float* Ecu0; const float* Ecu1; const float* Ecu2;
  const float* Eci0; const float* Eci1; const float* Eci2;
  float* Eut; float* Eit;
  const int* uids; const int* iids;
  float* svu1_0; float* svu1_1; float* svu1_2;
  float* svi1_0; float* svi1_1; float* svi1_2;
  float* svu0_0; float* svu0_1; float* svu0_2;
  float* svi0_0; float* svi0_1; float* svi0_2;
};

__global__ __launch_bounds__(256) void k_layer1_all(L1Args a){
  const int w = threadIdx.x >> 6, lane = threadIdx.x & 63;
  const int bid = blockIdx.x;
  if (bid < NB_SPU){
    dev_spmm1(a.ptr_u, a.ent_u, a.Eci0, a.Ecu0, a.Eu0, a.Eut, bid*4+w, lane);
  } else if (bid < NB_SPU+NB_SPI){
    dev_spmm1(a.ptr_i, a.ent_i, a.Ecu0, a.Eci0, a.Ei0, a.Eit, (bid-NB_SPU)*4+w, lane);
  } else if (bid < NB_SPU+NB_SPI+NB_B){
    dev_sspmm(a.uids, a.ptr_u, a.ent_u, a.Eci0, a.Eci1, a.Eci2,
              a.Ecu0, a.Ecu1, a.Ecu2, a.Eu0, a.svu1_0, a.svu1_1, a.svu1_2,
              (bid-(NB_SPU+NB_SPI))*4+w, lane);
  } else if (bid < NB_SPU+NB_SPI+2*NB_B){
    dev_sspmm(a.iids, a.ptr_i, a.ent_i, a.Ecu0, a.Ecu1, a.Ecu2,
              a.Eci0, a.Eci1, a.Eci2, a.Ei0, a.svi1_0, a.svi1_1, a.svi1_2,
              (bid-(NB_SPU+NB_SPI+NB_B))*4+w, lane);
  } else if (bid < NB_SPU+NB_SPI+3*NB_B){
    dev_gsave0(a.uids, a.Ecu0, a.Ecu1, a.Ecu2, a.Eu0,
               a.svu0_0, a.svu0_1, a.svu0_2, (bid-(NB_SPU+NB_SPI+2*NB_B))*4+w, lane);
  } else {
    dev_gsave0(a.iids, a.Eci0, a.Eci1, a.Eci2, a.Ei0,
               a.svi0_0, a.svi0_1, a.svi0_2, (bid-(NB_SPU+NB_SPI+3*NB_B))*4+w, lane);
  }
}

// ---------------- loss prep: 12 ops x 512 blocks ----------------
struct PrepArgs {
  const float* in[12];
  const float* W[12];
  float* out[12];
};

__global__ __launch_bounds__(256) void k_prep(PrepArgs pa){
  const int op = blockIdx.x >> 9;
  const int sub = blockIdx.x & 511;
  const int w = threadIdx.x >> 6, lane = threadIdx.x & 63;
  const int b = sub*4 + w;
  const float* in = pa.in[op];
  float* out = pa.out[op];
  const size_t o = ((size_t)b << 6) + lane;
  if (op < 8){
    const float v = in[o];
    const float n = fmaxf(sqrtf(wsum(v*v)), 1e-12f);
    out[o] = v/n;
  } else {
    const float* W = pa.W[op];
    const float x  = in[o];
    const float xn = fmaxf(sqrtf(wsum(x*x)), 1e-7f);
    const float sh = sinhf(xn), ch = coshf(xn);
    float vp = sh * x / xn;
    const float nv = fmaxf(sqrtf(ch*ch + wsum(vp*vp)), 1e-12f);
    const float v0 = ch/nv;
    vp /= nv;
    float acc = v0 * W[lane + 1];
    #pragma unroll
    for (int r=0; r<64; ++r){
      const float vr = __shfl(vp, r, 64);
      acc = fmaf(vr, W[(r+1)*65 + lane + 1], acc);
    }
    out[o] = acc;
  }
}

// ---------------- pair scores (8 pairs, 2-row register blocking) + lossr ----------------
struct PairArgs {
  const float* G[8]; const float* H[8];
  float2* pp;                       // [8][Bc][JS]
  const int* uids; const int* pos; const int* neg;
  const float* Eut; const float* Eit;
  float* rbuf;                      // [Bc] loss_r partials
};

__global__ __launch_bounds__(256,2) void k_pair_all(PairArgs pa){
  __shared__ float h_sh[64][68];
  const int bid = blockIdx.x;
  const int t = threadIdx.x;
  if (bid >= 4096){
    const int b = (bid-4096)*4 + (t>>6);
    const int lane = t & 63;
    const float ue = pa.Eut[((size_t)pa.uids[b] << 6) + lane];
    float s = 0.f;
    #pragma unroll
    for (int k=0;k<Kc;k++){
      const float dp = wsum(ue * pa.Eit[((size_t)pa.pos[b*Kc+k] << 6) + lane]);
      const float dn = wsum(ue * pa.Eit[((size_t)pa.neg[b*Kc+k] << 6) + lane]);
      const float tt = 1.f - dp + dn;
      s += tt > 0.f ? tt : 0.f;
    }
    if (lane == 0) pa.rbuf[b] = s;
    return;
  }
  const int pIdx = bid >> 9;
  const int wid = bid & 511;
  const int rg = wid >> 2, jb = wid & 3;
  const float* G = pa.G[pIdx];
  const float* H = pa.H[pIdx];
  const int rp = t >> 5, c = t & 31;
  const int r0 = rg*16 + rp*2;
  float4 g0[16], g1[16];
  {
    const float4* G0 = (const float4*)(G + ((size_t)r0 << 6));
    const float4* G1 = (const float4*)(G + ((size_t)(r0+1) << 6));
    #pragma unroll
    for (int q=0;q<16;q++){ g0[q] = G0[q]; g1[q] = G1[q]; }
  }
  float m0=-1e30f, s0=0.f, m1=-1e30f, s1=0.f;
  for (int jt = jb*JCH; jt < jb*JCH + JCH; jt += 64){
    __syncthreads();
    #pragma unroll
    for (int q0=0;q0<4;q0++){
      const int q = t + q0*256;
      const int row = q >> 4, col = q & 15;
      *(float4*)&h_sh[row][col*4] = ((const float4*)(H + ((size_t)(jt+row) << 6)))[col];
    }
    __syncthreads();
    #pragma unroll
    for (int jj=0; jj<2; ++jj){
      const int j = jj*32 + c;
      float d0 = 0.f, d1 = 0.f;
      #pragma unroll
      for (int q=0;q<16;q++){
        const float4 hv = *(const float4*)&h_sh[j][q*4];
        d0 = fmaf(g0[q].x, hv.x, d0); d0 = fmaf(g0[q].y, hv.y, d0);
        d0 = fmaf(g0[q].z, hv.z, d0); d0 = fmaf(g0[q].w, hv.w, d0);
        d1 = fmaf(g1[q].x, hv.x, d1); d1 = fmaf(g1[q].y, hv.y, d1);
        d1 = fmaf(g1[q].z, hv.z, d1); d1 = fmaf(g1[q].w, hv.w, d1);
      }
      d0 *= INV_Tc; d1 *= INV_Tc;
      { const float M = fmaxf(m0, d0); s0 = fmaf(s0, __expf(m0-M), __expf(d0-M)); m0 = M; }
      { const float M = fmaxf(m1, d1); s1 = fmaf(s1, __expf(m1-M), __expf(d1-M)); m1 = M; }
    }
  }
  #pragma unroll
  for (int off=16; off; off>>=1){
    { const float mo=__shfl_xor(m0,off,64), so=__shfl_xor(s0,off,64);
      const float M=fmaxf(m0,mo); s0 = s0*__expf(m0-M) + so*__expf(mo-M); m0=M; }
    { const float mo=__shfl_xor(m1,off,64), so=__shfl_xor(s1,off,64);
      const float M=fmaxf(m1,mo); s1 = s1*__expf(m1-M) + so*__expf(mo-M); m1=M; }
  }
  if (c == 0){
    float2* pp = pa.pp + (size_t)pIdx*Bc*JS;
    pp[(size_t)r0*JS + jb]     = make_float2(m0, s0);
    pp[(size_t)(r0+1)*JS + jb] = make_float2(m1, s1);
  }
}

// merge: 8 x 512 blocks; per-row result -> mres[pIdx*Bc + b] (no atomics)
struct MergeArgs {
  const float* G[8]; const float* H[8];
  const float2* pp; float* mres;    // [8][Bc]
};

__global__ __launch_bounds__(256) void k_merge_all(MergeArgs ma){
  const int pIdx = blockIdx.x >> 9;
  const int sub = blockIdx.x & 511;
  const int w = threadIdx.x >> 6, lane = threadIdx.x & 63;
  const int b = sub*4 + w;
  const float* G = ma.G[pIdx];
  const float* H = ma.H[pIdx];
  const size_t o = ((size_t)b << 6) + lane;
  const float d = wsum(G[o]*H[o]) * INV_Tc;
  const float2* pp = ma.pp + (size_t)pIdx*Bc*JS + (size_t)b*JS;
  const float2 p0 = pp[0], p1 = pp[1], p2 = pp[2], p3 = pp[3];
  float res;
  if ((pIdx & 1) == 0){
    const float M = fmaxf(fmaxf(p0.x,p1.x), fmaxf(p2.x,p3.x));
    const float S = p0.y*__expf(p0.x-M) + p1.y*__expf(p1.x-M)
                  + p2.y*__expf(p2.x-M) + p3.y*__expf(p3.x-M);
    res = M + logf(S) - d;
  } else {
    const float S = p0.y*__expf(p0.x) + p1.y*__expf(p1.x)
                  + p2.y*__expf(p2.x) + p3.y*__expf(p3.x);
    res = -logf(__expf(d)/(S + 1e-8f) + 1e-8f);
  }
  if (lane == 0) ma.mres[(size_t)pIdx*Bc + b] = res;
}

// final: single block sums rbuf (loss_r) + mres (loss_g even pIdx, loss_h odd)
__global__ __launch_bounds__(256) void k_final(const float* __restrict__ rbuf,
                                               const float* __restrict__ mres,
                                               float* __restrict__ out){
  __shared__ float shm[3][4];
  const int t = threadIdx.x;
  float sr = 0.f, shh = 0.f, sg = 0.f;
  for (int i=t; i<Bc; i+=256) sr += rbuf[i];
  #pragma unroll
  for (int p=0;p<8;p++){
    float acc = 0.f;
    for (int i=t; i<Bc; i+=256) acc += mres[(size_t)p*Bc + i];
    if (p & 1) shh += acc; else sg += acc;
  }
  sr = wsum(sr); shh = wsum(shh); sg = wsum(sg);
  const int w = t >> 6;
  if ((t & 63) == 0){ shm[0][w] = sr; shm[1][w] = shh; shm[2][w] = sg; }
  __syncthreads();
  if (t == 0){
    float R=0.f, Hh=0.f, Gg=0.f;
    #pragma unroll
    for (int q=0;q<4;q++){ R += shm[0][q]; Hh += shm[1][q]; Gg += shm[2][q]; }
    const float lr = R / (float)Bc;
    out[0] = lr + LHYPERc*Hh + Gg;
    out[1] = lr; out[2] = Hh; out[3] = Gg;
  }
}

// ---------------- host launch ----------------
extern "C" void kernel_launch(void* const* d_in, const int* in_sizes, int n_in,
                              void* d_out, int out_size, void* d_ws, size_t ws_size,
                              hipStream_t stream){
  const float* E_u0 = (const float*)d_in[0];
  const float* E_i0 = (const float*)d_in[1];
  // d_in[2], d_in[3] (S_u_0, S_i_0): col 0 == 0 forever, payload == E_*_0 -> unused.
  const float* Ws   = (const float*)d_in[4];
  const float* adj  = (const float*)d_in[5];
  const float* keep = (const float*)d_in[6];
  const int* rows = (const int*)d_in[7];
  const int* cols = (const int*)d_in[8];
  const int* uids = (const int*)d_in[9];
  const int* iids = (const int*)d_in[10];
  const int* pos  = (const int*)d_in[11];
  const int* neg  = (const int*)d_in[12];
  float* out = (float*)d_out;

  char* wsb = (char*)d_ws;
  size_t off = 0;
  auto alloc = [&](size_t bytes)->void*{
    void* p = (void*)(wsb + off);
    off += (bytes + 255) & ~(size_t)255;
    return p;
  };

  int* cmat_u = (int*)alloc((size_t)NB_BIN*NBK*4);
  int* cmat_i = (int*)alloc((size_t)NB_BIN*NBK*4);
  int* omat_u = (int*)alloc((size_t)NBK*NB_BIN*4);
  int* omat_i = (int*)alloc((size_t)NBK*NB_BIN*4);
  int* btot_u = (int*)alloc(256*4);
  int* btot_i = (int*)alloc(256*4);
  int* bbase_u = (int*)alloc(256*4);
  int* bbase_i = (int*)alloc(256*4);
  int* ptr_u = (int*)alloc((size_t)(N_Uc+1)*4);
  int* ptr_i = (int*)alloc((size_t)(N_Ic+1)*4);
  int2* buck_u = (int2*)alloc((size_t)Ec*8);
  int2* buck_i = (int2*)alloc((size_t)Ec*8);
  int2* ent_u = (int2*)alloc((size_t)Ec*8);
  int2* ent_i = (int2*)alloc((size_t)Ec*8);

  float* Ecu0 = (float*)alloc((size_t)NU64*4);
  float* Ecu1 = (float*)alloc((size_t)NU64*4);
  float* Ecu2 = (float*)alloc((size_t)NU64*4);
  float* Eu_t = (float*)alloc((size_t)NU64*4);
  float* Eci0 = (float*)alloc((size_t)NI64*4);
  float* Eci1 = (float*)alloc((size_t)NI64*4);
  float* Eci2 = (float*)alloc((size_t)NI64*4);
  float* Ei_t = (float*)alloc((size_t)NI64*4);

  float* sv_u[2][3], *sv_i[2][3];
  for (int l=0;l<2;l++) for (int ch=0;ch<3;ch++){
    sv_u[l][ch] = (float*)alloc((size_t)B64*4);
    sv_i[l][ch] = (float*)alloc((size_t)B64*4);
  }
  float* nrm_g[4], *nrm_u[4], *hmat[4];
  for (int p=0;p<4;p++){
    nrm_g[p] = (float*)alloc((size_t)B64*4);
    nrm_u[p] = (float*)alloc((size_t)B64*4);
    hmat[p]  = (float*)alloc((size_t)B64*4);
  }
  float2* pp = (float2*)alloc((size_t)8*Bc*JS*8);
  float* rbuf = (float*)alloc((size_t)Bc*4);
  float* mres = (float*)alloc((size_t)8*Bc*4);
  // total ws use ~= 237 MB

  // ---- bucketed CSR/CSC build, deterministic offsets (6 launches) ----
  k_count<<<NB_BIN,256,0,stream>>>(rows, cols, cmat_u, cmat_i);
  k_oscan<<<2*NBK,512,0,stream>>>(cmat_u, cmat_i, omat_u, omat_i, btot_u, btot_i);
  k_bbase<<<1,256,0,stream>>>(btot_u, btot_i, bbase_u, bbase_i);
  BinArgs ba{rows, cols, adj, keep, omat_u, omat_i, bbase_u, bbase_i, buck_u, buck_i};
  k_binscatter<0><<<NB_BIN,256,0,stream>>>(ba);
  k_binscatter<1><<<NB_BIN,256,0,stream>>>(ba);
  SortArgs soa{buck_u, buck_i, bbase_u, bbase_i, ptr_u, ptr_i, ent_u, ent_i};
  k_bucketsort<<<2*NBK,512,0,stream>>>(soa);

  // ---- layer 0 (1 launch) ----
  SpmmArgs sa{ptr_u, ent_u, ptr_i, ent_i, E_u0, E_i0,
              Ecu0, Ecu1, Ecu2, Eu_t, Eci0, Eci1, Eci2, Ei_t};
  k_spmm3_all<<<NB_SPU+NB_SPI,256,0,stream>>>(sa);

  // ---- layer 1 + sampled + layer-0 saves (1 launch) ----
  L1Args la{ptr_u, ent_u, ptr_i, ent_i, E_u0, E_i0,
            Ecu0, Ecu1, Ecu2, Eci0, Eci1, Eci2, Eu_t, Ei_t, uids, iids,
            sv_u[1][0], sv_u[1][1], sv_u[1][2], sv_i[1][0], sv_i[1][1], sv_i[1][2],
            sv_u[0][0], sv_u[0][1], sv_u[0][2], sv_i[0][0], sv_i[0][1], sv_i[0][2]};
  k_layer1_all<<<NB_SPU+NB_SPI+4*NB_B,256,0,stream>>>(la);

  // ---- loss prep (1 launch): p = l*2+side ----
  PrepArgs pra{};
  for (int l=0;l<2;l++) for (int side=0; side<2; side++){
    const int p = l*2+side;
    float** svs = side ? sv_i[l] : sv_u[l];
    pra.in[p]   = svs[0]; pra.out[p]   = nrm_g[p];
    pra.in[4+p] = svs[2]; pra.out[4+p] = nrm_u[p];
    pra.in[8+p] = svs[1]; pra.out[8+p] = hmat[p];
    pra.W[8+p]  = Ws + (size_t)l*65*65;
  }
  k_prep<<<12*NB_B,256,0,stream>>>(pra);

  // ---- pair scores + lossr (1 launch) ----
  PairArgs paa{};
  for (int p=0;p<4;p++){
    paa.G[2*p]   = nrm_g[p]; paa.H[2*p]   = nrm_u[p];   // loss_g
    paa.G[2*p+1] = nrm_g[p]; paa.H[2*p+1] = hmat[p];    // loss_h
  }
  paa.pp = pp; paa.uids = uids; paa.pos = pos; paa.neg = neg;
  paa.Eut = Eu_t; paa.Eit = Ei_t; paa.rbuf = rbuf;
  k_pair_all<<<4096+NB_B,256,0,stream>>>(paa);

  // ---- merge (1 launch) + final ----
  MergeArgs mga{};
  for (int p=0;p<8;p++){ mga.G[p] = paa.G[p]; mga.H[p] = paa.H[p]; }
  mga.pp = pp; mga.mres = mres;
  k_merge_all<<<8*NB_B,256,0,stream>>>(mga);

  k_final<<<1,256,0,stream>>>(rbuf, mres, out);
}